// Round 1
// baseline (6659.779 us; speedup 1.0000x reference)
//
#include <hip/hip_runtime.h>
#include <hip/hip_bf16.h>

typedef __hip_bfloat16 bf16;

// problem constants (fixed instance)
#define BB    2
#define LL    6
#define NWIN  64     // X*Y
#define PP    49     // w1*w2
#define DIMM  256
#define HEADS 8
#define CHN   32
#define SS    294    // LL*PP
#define KS_STRIDE 40 // bf16 elems per k row in LDS (80B, 16B-aligned, conflict-free)
#define VT_STRIDE 33 // f32 elems per vt row in LDS (+1 pad)

__device__ __forceinline__ float bflo(unsigned int u) { return __uint_as_float(u << 16); }
__device__ __forceinline__ float bfhi(unsigned int u) { return __uint_as_float(u & 0xffff0000u); }

// ---------------- kernel 0: transpose Wo (256x256) -> WoT ----------------
__global__ __launch_bounds__(256) void k_transpose(const float* __restrict__ Wo,
                                                   float* __restrict__ WoT)
{
    __shared__ float t[32][33];
    const int bx = blockIdx.x, by = blockIdx.y;
    const int tx = threadIdx.x, ty = threadIdx.y; // (32,8)
    #pragma unroll
    for (int r = 0; r < 32; r += 8)
        t[ty + r][tx] = Wo[(by*32 + ty + r)*DIMM + bx*32 + tx];
    __syncthreads();
    #pragma unroll
    for (int r = 0; r < 32; r += 8)
        WoT[(bx*32 + ty + r)*DIMM + by*32 + tx] = t[tx][ty + r];
}

// ---------------- shared GEMM helper: NR rows x 256 cols, K=256 ----------------
template<int NR>
__device__ __forceinline__ void gemm_rows(const float* xs, const float* __restrict__ W,
                                          const int tid, const int r0, float acc[NR])
{
    for (int d0 = 0; d0 < DIMM; d0 += 4) {
        const float w0 = W[(d0+0)*DIMM + tid];
        const float w1 = W[(d0+1)*DIMM + tid];
        const float w2 = W[(d0+2)*DIMM + tid];
        const float w3 = W[(d0+3)*DIMM + tid];
        #pragma unroll
        for (int r = 0; r < NR; ++r) {
            const float4 xv = *(const float4*)&xs[(r0+r)*DIMM + d0];
            float a = acc[r];
            a = fmaf(xv.x, w0, a);
            a = fmaf(xv.y, w1, a);
            a = fmaf(xv.z, w2, a);
            a = fmaf(xv.w, w3, a);
            acc[r] = a;
        }
    }
}

// ---------------- kernel 1: QKV projection ----------------
// block = one (b,l,n): 49 rows x 256. q,k,v written bf16 to ws as [ (b*64+n)*8+m ][ l*49+p ][ c ]
__global__ __launch_bounds__(256) void k_qkv(
    const float* __restrict__ x,
    const float* __restrict__ Wq, const float* __restrict__ bq,
    const float* __restrict__ Wk, const float* __restrict__ bk,
    const float* __restrict__ Wv, const float* __restrict__ bv,
    const int* __restrict__ atype,
    bf16* __restrict__ q, bf16* __restrict__ k, bf16* __restrict__ v)
{
    __shared__ float xs[PP*DIMM]; // 50176 B
    const int tid = threadIdx.x;
    const int bid = blockIdx.x;              // (b*6+l)*64+n
    const int n = bid & 63;
    const int l = (bid >> 6) % LL;
    const int b = bid / (LL*NWIN);
    const float* xp = x + (size_t)bid * (PP*DIMM);
    for (int idx = tid; idx < PP*DIMM; idx += 256) xs[idx] = xp[idx];
    __syncthreads();
    const int t = (l == 0) ? 0 : atype[0];
    const int m = tid >> 5, c = tid & 31;
    const size_t obase = ((size_t)((b*NWIN + n)*HEADS + m))*(SS*CHN) + (size_t)(l*PP)*CHN + c;

    for (int tz = 0; tz < 3; ++tz) {
        const float* W    = (tz == 0 ? Wq : tz == 1 ? Wk : Wv) + t*DIMM*DIMM;
        const float* bias = (tz == 0 ? bq : tz == 1 ? bk : bv) + t*DIMM;
        bf16* dst = (tz == 0 ? q : tz == 1 ? k : v);
        const float scale = (tz == 0) ? 0.17677669529663687f : 1.0f; // ch^-0.5 on q (incl bias)
        const float bb = bias[tid];
        {
            float acc[17];
            #pragma unroll
            for (int r = 0; r < 17; ++r) acc[r] = bb;
            gemm_rows<17>(xs, W, tid, 0, acc);
            #pragma unroll
            for (int r = 0; r < 17; ++r) dst[obase + (size_t)(0 + r)*CHN] = __float2bfloat16(acc[r]*scale);
        }
        {
            float acc[16];
            #pragma unroll
            for (int r = 0; r < 16; ++r) acc[r] = bb;
            gemm_rows<16>(xs, W, tid, 17, acc);
            #pragma unroll
            for (int r = 0; r < 16; ++r) dst[obase + (size_t)(17 + r)*CHN] = __float2bfloat16(acc[r]*scale);
        }
        {
            float acc[16];
            #pragma unroll
            for (int r = 0; r < 16; ++r) acc[r] = bb;
            gemm_rows<16>(xs, W, tid, 33, acc);
            #pragma unroll
            for (int r = 0; r < 16; ++r) dst[obase + (size_t)(33 + r)*CHN] = __float2bfloat16(acc[r]*scale);
        }
    }
}

// ---------------- kernel 2: hetero attention per (b,n,m) ----------------
__global__ __launch_bounds__(256) void k_attn(
    const bf16* __restrict__ q, const bf16* __restrict__ kk_, const bf16* __restrict__ v,
    const float* __restrict__ rel_att, const float* __restrict__ rel_msg,
    const float* __restrict__ bias_table, const int* __restrict__ atype,
    float* __restrict__ o_pre)
{
    __shared__ unsigned short ks[SS*KS_STRIDE];   // 23520 B  (bf16 bits)
    __shared__ float vts[SS*VT_STRIDE];           // 38808 B
    __shared__ float qwl[4*4*192];                // 12288 B  [wave][row][j*32+f]
    __shared__ unsigned short attnl[4*2*304];     //  4864 B  [wave][pairslot][s2] bf16
                                                  // total 79480 B -> 2 blocks/CU
    const int tid  = threadIdx.x;
    const int w    = tid >> 6;
    const int lane = tid & 63;
    const int hh   = lane >> 5;
    const int cl   = lane & 31;
    const int bid  = blockIdx.x;       // (b*64+n)*8+m
    const int m = bid & 7;
    const int n = (bid >> 3) & 63;
    const int b = bid >> 9;
    const int at = atype[0];
    (void)n; (void)b;

    const size_t slab = (size_t)bid * (SS*CHN);
    const bf16* qs  = q   + slab;
    const unsigned short* ksg = (const unsigned short*)(kk_ + slab);
    const unsigned short* vsg = (const unsigned short*)(v   + slab);

    // stage K (all rows, stride-40 bf16)
    for (int idx = tid; idx < SS*CHN/2; idx += 256) {
        const int s2 = idx >> 4;
        const int c2 = (idx & 15) << 1;
        *(ushort2*)&ks[s2*KS_STRIDE + c2] = ((const ushort2*)ksg)[idx];
    }

    float watt[3][32]; // per-lane W_att columns: slot -> j = slot*2+hh, f = cl

    for (int i = 0; i < LL; ++i) {
        const int ti = (i == 0) ? 0 : at;
        __syncthreads(); // K staged (i=0); prior i's readers done before vts rebuild

        // build vt[s2][c] = sum_f Wmsg[pair(i,j)][m][c][f] * v[s2][f]
        for (int idx = tid; idx < SS*CHN; idx += 256) {
            const int s2 = idx >> 5;
            const int c  = idx & 31;
            const int j  = s2 / 49;
            const int pair = ti*2 + ((j == 0) ? 0 : at);
            const float* wm = rel_msg + (size_t)((pair*HEADS + m)*CHN + c)*CHN;
            const unsigned short* vv = vsg + s2*CHN;
            float acc = 0.f;
            #pragma unroll
            for (int f0 = 0; f0 < CHN; f0 += 4) {
                const float4 a = *(const float4*)&wm[f0];
                const uint2 uv = *(const uint2*)&vv[f0];
                acc = fmaf(bflo(uv.x), a.x, acc);
                acc = fmaf(bfhi(uv.x), a.y, acc);
                acc = fmaf(bflo(uv.y), a.z, acc);
                acc = fmaf(bfhi(uv.y), a.w, acc);
            }
            vts[s2*VT_STRIDE + c] = acc;
        }
        // load W_att columns into registers (reused over 49 rows)
        #pragma unroll
        for (int s = 0; s < 3; ++s) {
            const int j = s*2 + hh;
            const int pair = ti*2 + ((j == 0) ? 0 : at);
            const float* wa = rel_att + (size_t)((pair*HEADS + m)*CHN)*CHN + cl;
            #pragma unroll
            for (int c = 0; c < 32; ++c) watt[s][c] = wa[c*CHN];
        }
        __syncthreads(); // vts ready

        for (int p0 = w*4; p0 < PP; p0 += 16) {
            // q rows p0..p0+3 into regs: lane (hh,cl) holds rows p0+hh and p0+2+hh
            const int pA = p0 + hh, pB = p0 + 2 + hh;
            float qv0 = __bfloat162float(qs[(i*PP + (pA < PP ? pA : PP-1))*CHN + cl]);
            if (pA >= PP) qv0 = 0.f;
            float qv1 = __bfloat162float(qs[(i*PP + (pB < PP ? pB : PP-1))*CHN + cl]);
            if (pB >= PP) qv1 = 0.f;

            // qw[row][slot] = sum_c q[row][c] * watt[slot][c]   (f = cl, j = slot*2+hh)
            float qw[4][3];
            #pragma unroll
            for (int rr = 0; rr < 4; ++rr)
                #pragma unroll
                for (int s = 0; s < 3; ++s) qw[rr][s] = 0.f;
            #pragma unroll
            for (int c = 0; c < 32; ++c) {
                const float q0 = __shfl(qv0, c);
                const float q1 = __shfl(qv0, 32 + c);
                const float q2 = __shfl(qv1, c);
                const float q3 = __shfl(qv1, 32 + c);
                #pragma unroll
                for (int s = 0; s < 3; ++s) {
                    const float ww = watt[s][c];
                    qw[0][s] = fmaf(q0, ww, qw[0][s]);
                    qw[1][s] = fmaf(q1, ww, qw[1][s]);
                    qw[2][s] = fmaf(q2, ww, qw[2][s]);
                    qw[3][s] = fmaf(q3, ww, qw[3][s]);
                }
            }
            #pragma unroll
            for (int rr = 0; rr < 4; ++rr)
                #pragma unroll
                for (int s = 0; s < 3; ++s)
                    qwl[(w*4 + rr)*192 + (s*2 + hh)*32 + cl] = qw[rr][s];
            __builtin_amdgcn_sched_barrier(0); // keep ds_writes before ds_reads (same wave, HW in-order)

            int ph[4], pw[4];
            #pragma unroll
            for (int rr = 0; rr < 4; ++rr) {
                const int p = (p0 + rr < PP) ? (p0 + rr) : (PP - 1);
                ph[rr] = p / 7;
                pw[rr] = p - ph[rr]*7;
            }

            // scores: lane covers s2 = r*64+lane
            float sc[4][5];
            #pragma unroll
            for (int r = 0; r < 5; ++r) {
                const int s2 = r*64 + lane;
                const bool valid = (s2 < SS);
                const int s2c = valid ? s2 : 0;
                const int j  = s2c / 49;
                const int q2 = s2c - j*49;
                const int qh = q2 / 7;
                const int qq = q2 - qh*7;
                float dot[4] = {0.f, 0.f, 0.f, 0.f};
                const int kb = s2c*KS_STRIDE;
                const int qb = w*4*192 + j*32;
                #pragma unroll
                for (int c0 = 0; c0 < 32; c0 += 8) {
                    const uint4 kv = *(const uint4*)&ks[kb + c0];
                    const float k0 = bflo(kv.x), k1 = bfhi(kv.x);
                    const float k2 = bflo(kv.y), k3 = bfhi(kv.y);
                    const float k4 = bflo(kv.z), k5 = bfhi(kv.z);
                    const float k6 = bflo(kv.w), k7 = bfhi(kv.w);
                    #pragma unroll
                    for (int rr = 0; rr < 4; ++rr) {
                        const float4 a0 = *(const float4*)&qwl[qb + rr*192 + c0];
                        const float4 a1 = *(const float4*)&qwl[qb + rr*192 + c0 + 4];
                        float d = dot[rr];
                        d = fmaf(k0, a0.x, d); d = fmaf(k1, a0.y, d);
                        d = fmaf(k2, a0.z, d); d = fmaf(k3, a0.w, d);
                        d = fmaf(k4, a1.x, d); d = fmaf(k5, a1.y, d);
                        d = fmaf(k6, a1.z, d); d = fmaf(k7, a1.w, d);
                        dot[rr] = d;
                    }
                }
                const int dji = (i - j + 5)*169;
                #pragma unroll
                for (int rr = 0; rr < 4; ++rr) {
                    const int bidx = dji + (ph[rr] - qh + 6)*13 + (pw[rr] - qq + 6);
                    sc[rr][r] = valid ? (dot[rr] + bias_table[bidx*HEADS + m]) : -1e30f;
                }
            }

            // softmax + PV, two rows at a time
            #pragma unroll
            for (int pr = 0; pr < 2; ++pr) {
                const int rA = pr*2, rBq = pr*2 + 1;
                float mA = fmaxf(fmaxf(fmaxf(sc[rA][0], sc[rA][1]), fmaxf(sc[rA][2], sc[rA][3])), sc[rA][4]);
                float mB = fmaxf(fmaxf(fmaxf(sc[rBq][0], sc[rBq][1]), fmaxf(sc[rBq][2], sc[rBq][3])), sc[rBq][4]);
                #pragma unroll
                for (int off = 32; off > 0; off >>= 1) {
                    mA = fmaxf(mA, __shfl_xor(mA, off));
                    mB = fmaxf(mB, __shfl_xor(mB, off));
                }
                float eA[5], eB[5];
                float sA = 0.f, sB = 0.f;
                #pragma unroll
                for (int r = 0; r < 5; ++r) {
                    const bool valid = (r*64 + lane) < SS;
                    eA[r] = valid ? __expf(sc[rA][r]  - mA) : 0.f;
                    eB[r] = valid ? __expf(sc[rBq][r] - mB) : 0.f;
                    sA += eA[r]; sB += eB[r];
                }
                #pragma unroll
                for (int off = 32; off > 0; off >>= 1) {
                    sA += __shfl_xor(sA, off);
                    sB += __shfl_xor(sB, off);
                }
                const float iA = 1.0f / sA, iB = 1.0f / sB;
                #pragma unroll
                for (int r = 0; r < 5; ++r) {
                    const int s2 = r*64 + lane;
                    if (s2 < SS) {
                        attnl[(w*2 + 0)*304 + s2] = __bfloat16_as_ushort(__float2bfloat16(eA[r]*iA));
                        attnl[(w*2 + 1)*304 + s2] = __bfloat16_as_ushort(__float2bfloat16(eB[r]*iB));
                    }
                }
                __builtin_amdgcn_sched_barrier(0);
                float oA = 0.f, oB = 0.f;
                for (int u = 0; u < 147; ++u) {
                    const int s2 = 2*u + hh;
                    const float vt = vts[s2*VT_STRIDE + cl];
                    oA = fmaf(bflo((unsigned int)attnl[(w*2 + 0)*304 + s2]), vt, oA);
                    oB = fmaf(bflo((unsigned int)attnl[(w*2 + 1)*304 + s2]), vt, oB);
                }
                __builtin_amdgcn_sched_barrier(0);
                oA += __shfl_xor(oA, 32);
                oB += __shfl_xor(oB, 32);
                if (lane < 32) {
                    const int pOutA = p0 + pr*2;
                    const int pOutB = pOutA + 1;
                    const size_t rowbase = ((size_t)(b*LL + i)*NWIN + n)*PP;
                    if (pOutA < PP) o_pre[(rowbase + pOutA)*DIMM + m*CHN + cl] = oA;
                    if (pOutB < PP) o_pre[(rowbase + pOutB)*DIMM + m*CHN + cl] = oB;
                }
            }
        }
    }
}

// ---------------- kernel 3: out = o_pre @ Wo^T ----------------
__global__ __launch_bounds__(256) void k_out(
    const float* __restrict__ pre, const float* __restrict__ WoT,
    float* __restrict__ out)
{
    __shared__ float xs[PP*DIMM];
    const int tid = threadIdx.x;
    const int bid = blockIdx.x;
    const float* xp = pre + (size_t)bid * (PP*DIMM);
    for (int idx = tid; idx < PP*DIMM; idx += 256) xs[idx] = xp[idx];
    __syncthreads();
    float* op = out + (size_t)bid * (PP*DIMM);
    {
        float acc[17];
        #pragma unroll
        for (int r = 0; r < 17; ++r) acc[r] = 0.f;
        gemm_rows<17>(xs, WoT, tid, 0, acc);
        #pragma unroll
        for (int r = 0; r < 17; ++r) op[(size_t)(0 + r)*DIMM + tid] = acc[r];
    }
    {
        float acc[16];
        #pragma unroll
        for (int r = 0; r < 16; ++r) acc[r] = 0.f;
        gemm_rows<16>(xs, WoT, tid, 17, acc);
        #pragma unroll
        for (int r = 0; r < 16; ++r) op[(size_t)(17 + r)*DIMM + tid] = acc[r];
    }
    {
        float acc[16];
        #pragma unroll
        for (int r = 0; r < 16; ++r) acc[r] = 0.f;
        gemm_rows<16>(xs, WoT, tid, 33, acc);
        #pragma unroll
        for (int r = 0; r < 16; ++r) op[(size_t)(33 + r)*DIMM + tid] = acc[r];
    }
}

extern "C" void kernel_launch(void* const* d_in, const int* in_sizes, int n_in,
                              void* d_out, int out_size, void* d_ws, size_t ws_size,
                              hipStream_t stream)
{
    (void)in_sizes; (void)n_in; (void)out_size; (void)ws_size;
    const float* x        = (const float*)d_in[0];
    const float* Wq       = (const float*)d_in[1];
    const float* bq       = (const float*)d_in[2];
    const float* Wk       = (const float*)d_in[3];
    const float* bk       = (const float*)d_in[4];
    const float* Wv       = (const float*)d_in[5];
    const float* bv       = (const float*)d_in[6];
    const float* rel_att  = (const float*)d_in[7];
    const float* rel_msg  = (const float*)d_in[8];
    const float* bias_tab = (const float*)d_in[9];
    const float* Wo       = (const float*)d_in[10];
    const int*   atype    = (const int*)d_in[11];
    float* out = (float*)d_out;

    // workspace layout (bytes):
    //  WoT f32:   [0, 262144)
    //  q bf16:    [262144, +19267584)
    //  k bf16:    next 19267584
    //  v bf16:    next 19267584
    //  o_pre f32: next 38535168   -> total 96,600,064 B
    char* ws = (char*)d_ws;
    float* WoT  = (float*)ws;
    bf16*  qb   = (bf16*)(ws + 262144);
    bf16*  kb   = (bf16*)(ws + 262144 + 1*19267584);
    bf16*  vb   = (bf16*)(ws + 262144 + 2*19267584);
    float* o_pre= (float*)(ws + 262144 + 3*19267584);

    k_transpose<<<dim3(8, 8), dim3(32, 8), 0, stream>>>(Wo, WoT);
    k_qkv<<<BB*LL*NWIN, 256, 0, stream>>>(x, Wq, bq, Wk, bk, Wv, bv, atype, qb, kb, vb);
    k_attn<<<BB*NWIN*HEADS, 256, 0, stream>>>(qb, kb, vb, rel_att, rel_msg, bias_tab, atype, o_pre);
    k_out<<<BB*LL*NWIN, 256, 0, stream>>>(o_pre, WoT, out);
}

// Round 2
// 594.684 us; speedup vs baseline: 11.1988x; 11.1988x over previous
//
#include <hip/hip_runtime.h>
#include <hip/hip_bf16.h>

typedef __hip_bfloat16 bf16;
typedef unsigned short u16;
typedef short bf16x8 __attribute__((ext_vector_type(8)));
typedef float f32x4  __attribute__((ext_vector_type(4)));

// problem constants (fixed instance)
#define BB    2
#define LL    6
#define NWIN  64     // X*Y
#define PP    49     // w1*w2
#define DIMM  256
#define HEADS 8
#define CHN   32
#define SS    294    // LL*PP

__device__ __forceinline__ u16 bfbits(float x) { return __bfloat16_as_ushort(__float2bfloat16(x)); }
__device__ __forceinline__ f32x4 mfma16(bf16x8 a, bf16x8 b, f32x4 c) {
    return __builtin_amdgcn_mfma_f32_16x16x32_bf16(a, b, c, 0, 0, 0);
}

// ---------------- kernel 0: transpose Wo (256x256) -> WoT ----------------
__global__ __launch_bounds__(256) void k_transpose(const float* __restrict__ Wo,
                                                   float* __restrict__ WoT)
{
    __shared__ float t[32][33];
    const int bx = blockIdx.x, by = blockIdx.y;
    const int tx = threadIdx.x, ty = threadIdx.y; // (32,8)
    #pragma unroll
    for (int r = 0; r < 32; r += 8)
        t[ty + r][tx] = Wo[(by*32 + ty + r)*DIMM + bx*32 + tx];
    __syncthreads();
    #pragma unroll
    for (int r = 0; r < 32; r += 8)
        WoT[(bx*32 + ty + r)*DIMM + by*32 + tx] = t[tx][ty + r];
}

// ---------------- kernel 0b: convert rel weights to bf16 (att transposed) ----------------
__global__ __launch_bounds__(256) void k_prep(const float* __restrict__ ra,
                                              const float* __restrict__ rm,
                                              u16* __restrict__ raT, u16* __restrict__ rmb)
{
    const int idx = blockIdx.x*256 + threadIdx.x;
    if (idx < 4*HEADS*CHN*CHN) {
        const int pm = idx >> 10, cf = idx & 1023, c = cf >> 5, f = cf & 31;
        raT[(pm << 10) + (f << 5) + c] = bfbits(ra[idx]);   // [pair][m][f][c]  (B^T for qw build)
        rmb[idx] = bfbits(rm[idx]);                          // [pair][m][c][f]  (B^T for out xform)
    }
}

// ---------------- shared GEMM helper: NR rows x 256 cols, K=256 ----------------
template<int NR>
__device__ __forceinline__ void gemm_rows(const float* xs, const float* __restrict__ W,
                                          const int tid, const int r0, float acc[NR])
{
    for (int d0 = 0; d0 < DIMM; d0 += 4) {
        const float w0 = W[(d0+0)*DIMM + tid];
        const float w1 = W[(d0+1)*DIMM + tid];
        const float w2 = W[(d0+2)*DIMM + tid];
        const float w3 = W[(d0+3)*DIMM + tid];
        #pragma unroll
        for (int r = 0; r < NR; ++r) {
            const float4 xv = *(const float4*)&xs[(r0+r)*DIMM + d0];
            float a = acc[r];
            a = fmaf(xv.x, w0, a);
            a = fmaf(xv.y, w1, a);
            a = fmaf(xv.z, w2, a);
            a = fmaf(xv.w, w3, a);
            acc[r] = a;
        }
    }
}

// ---------------- kernel 1: QKV projection ----------------
__global__ __launch_bounds__(256) void k_qkv(
    const float* __restrict__ x,
    const float* __restrict__ Wq, const float* __restrict__ bq,
    const float* __restrict__ Wk, const float* __restrict__ bk,
    const float* __restrict__ Wv, const float* __restrict__ bv,
    const int* __restrict__ atype,
    bf16* __restrict__ q, bf16* __restrict__ k, bf16* __restrict__ v)
{
    __shared__ float xs[PP*DIMM]; // 50176 B
    const int tid = threadIdx.x;
    const int bid = blockIdx.x;              // (b*6+l)*64+n
    const int n = bid & 63;
    const int l = (bid >> 6) % LL;
    const int b = bid / (LL*NWIN);
    const float* xp = x + (size_t)bid * (PP*DIMM);
    for (int idx = tid; idx < PP*DIMM; idx += 256) xs[idx] = xp[idx];
    __syncthreads();
    const int t = (l == 0) ? 0 : atype[0];
    const int m = tid >> 5, c = tid & 31;
    const size_t obase = ((size_t)((b*NWIN + n)*HEADS + m))*(SS*CHN) + (size_t)(l*PP)*CHN + c;

    for (int tz = 0; tz < 3; ++tz) {
        const float* W    = (tz == 0 ? Wq : tz == 1 ? Wk : Wv) + t*DIMM*DIMM;
        const float* bias = (tz == 0 ? bq : tz == 1 ? bk : bv) + t*DIMM;
        bf16* dst = (tz == 0 ? q : tz == 1 ? k : v);
        const float scale = (tz == 0) ? 0.17677669529663687f : 1.0f;
        const float bb = bias[tid];
        {
            float acc[17];
            #pragma unroll
            for (int r = 0; r < 17; ++r) acc[r] = bb;
            gemm_rows<17>(xs, W, tid, 0, acc);
            #pragma unroll
            for (int r = 0; r < 17; ++r) dst[obase + (size_t)(0 + r)*CHN] = __float2bfloat16(acc[r]*scale);
        }
        {
            float acc[16];
            #pragma unroll
            for (int r = 0; r < 16; ++r) acc[r] = bb;
            gemm_rows<16>(xs, W, tid, 17, acc);
            #pragma unroll
            for (int r = 0; r < 16; ++r) dst[obase + (size_t)(17 + r)*CHN] = __float2bfloat16(acc[r]*scale);
        }
        {
            float acc[16];
            #pragma unroll
            for (int r = 0; r < 16; ++r) acc[r] = bb;
            gemm_rows<16>(xs, W, tid, 33, acc);
            #pragma unroll
            for (int r = 0; r < 16; ++r) dst[obase + (size_t)(33 + r)*CHN] = __float2bfloat16(acc[r]*scale);
        }
    }
}

// ---------------- kernel 2: MFMA hetero attention per (b,n,m) ----------------
// LDS layout (u16 units):
//   vT    [32][328]   base 0       (v transposed, s2-major cols; cols>=294 zeroed)
//   vT0   [32][72]    base 10496   (v rows 0..48, cols 49..63 zeroed)
//   qws   [4][16][72] base 12800   (per-wave qw / agg staging strip)
//   strip [4][16][328] base 17408  (per-wave attn-weight strip, cols>=294 zeroed)
// total 38400 u16 = 76800 B -> 2 blocks/CU
__global__ __launch_bounds__(256) void k_attn(
    const u16* __restrict__ q, const u16* __restrict__ kk_, const u16* __restrict__ v,
    const u16* __restrict__ raT, const u16* __restrict__ rmb,
    const float* __restrict__ bias_table, const int* __restrict__ atype,
    float* __restrict__ o_pre)
{
    extern __shared__ __align__(16) u16 lds[];
    u16* vT    = lds;
    u16* vT0   = lds + 10496;
    u16* qws   = lds + 12800;
    u16* strip = lds + 17408;

    const int tid  = threadIdx.x;
    const int w    = tid >> 6;
    const int lane = tid & 63;
    const int g4   = lane >> 4;
    const int c16  = lane & 15;
    const int bid  = blockIdx.x;       // (b*64+n)*8+m
    const int m    = bid & 7;
    const int nwin = (bid >> 3) & 63;
    const int b    = bid >> 9;
    const int at   = atype[0];

    const size_t slab = (size_t)bid * (SS*CHN);
    const u16* qs  = q   + slab;
    const u16* ksg = kk_ + slab;
    const u16* vsg = v   + slab;

    u16* qws_w   = qws   + w*(16*72);
    u16* strip_w = strip + w*(16*328);

    // ---- zero pads + stage vT/vT0 ----
    for (int idx = tid; idx < 32*26; idx += 256) vT[(idx/26)*328 + 294 + (idx%26)] = 0;
    for (int idx = tid; idx < 32*15; idx += 256) vT0[(idx/15)*72 + 49 + (idx%15)] = 0;
    for (int idx = tid; idx < 4*16*26; idx += 256) {
        const int ww = idx/(16*26), rem = idx%(16*26);
        strip[ww*(16*328) + (rem/26)*328 + 294 + (rem%26)] = 0;
    }
    for (int idx = tid; idx < SS*CHN; idx += 256) {
        const int s2 = idx >> 5, f = idx & 31;
        const u16 val = vsg[idx];
        vT[f*328 + s2] = val;
        if (s2 < 49) vT0[f*72 + s2] = val;
    }
    __syncthreads();

    const f32x4 zero4 = {0.f, 0.f, 0.f, 0.f};

    // 20 jobs: jobs 0..18 -> s1-tile = job; job 3 uses ti=0 (keeps only row 48);
    // job 19 -> s1-tile 3 with ti=at (keeps rows 49..63).
    for (int job = w; job < 20; job += 4) {
        const int tile = (job == 19) ? 3 : job;
        const int tiv  = (job <= 3) ? 0 : at;
        const int pair0 = tiv*2;        // tj = 0
        const int pair1 = tiv*2 + at;   // tj = at

        // ---- phase A: qw build (fold W_att into q) ----
        const int rowA = tile*16 + c16;
        const bf16x8 aq = *(const bf16x8*)(qs + rowA*CHN + g4*8);
        f32x4 cqw00, cqw01, cqw10, cqw11;
        {
            const u16* base0 = raT + (pair0*HEADS + m)*1024;
            const u16* base1 = raT + (pair1*HEADS + m)*1024;
            const bf16x8 b00 = *(const bf16x8*)(base0 + (c16     )*32 + g4*8);
            const bf16x8 b01 = *(const bf16x8*)(base0 + (16 + c16)*32 + g4*8);
            const bf16x8 b10 = *(const bf16x8*)(base1 + (c16     )*32 + g4*8);
            const bf16x8 b11 = *(const bf16x8*)(base1 + (16 + c16)*32 + g4*8);
            cqw00 = mfma16(aq, b00, zero4);
            cqw01 = mfma16(aq, b01, zero4);
            cqw10 = mfma16(aq, b10, zero4);
            cqw11 = mfma16(aq, b11, zero4);
        }
        #pragma unroll
        for (int r = 0; r < 4; ++r) {
            const int row = g4*4 + r;
            qws_w[row*72 +      c16] = bfbits(cqw00[r]);
            qws_w[row*72 + 16 + c16] = bfbits(cqw01[r]);
            qws_w[row*72 + 32 + c16] = bfbits(cqw10[r]);
            qws_w[row*72 + 48 + c16] = bfbits(cqw11[r]);
        }
        const bf16x8 A0 = *(const bf16x8*)(qws_w + c16*72 +      g4*8);
        const bf16x8 A1 = *(const bf16x8*)(qws_w + c16*72 + 32 + g4*8);

        // ---- phase B: sim = qw_sel @ k^T ----
        f32x4 acc[19];
        #pragma unroll
        for (int t = 0; t < 3; ++t) {
            const bf16x8 bk = *(const bf16x8*)(ksg + (t*16 + c16)*CHN + g4*8);
            acc[t] = mfma16(A0, bk, zero4);
        }
        {
            const bf16x8 bk = *(const bf16x8*)(ksg + (3*16 + c16)*CHN + g4*8);
            const f32x4 cA = mfma16(A0, bk, zero4);
            const f32x4 cB = mfma16(A1, bk, zero4);
            #pragma unroll
            for (int r = 0; r < 4; ++r) acc[3][r] = (c16 == 0) ? cA[r] : cB[r]; // s2=48 is j=0
        }
        #pragma unroll
        for (int t = 4; t < 19; ++t) {
            const bf16x8 bk = *(const bf16x8*)(ksg + (t*16 + c16)*CHN + g4*8);
            acc[t] = mfma16(A1, bk, zero4);
        }

        // ---- bias add: bidx = rowcode - colcode + 929 ----
        int rowcode[4];
        #pragma unroll
        for (int r = 0; r < 4; ++r) {
            const int s1r = tile*16 + g4*4 + r;
            const int s1c = (s1r < SS) ? s1r : 0;
            const int i1 = s1c / 49, p1 = s1c - i1*49;
            const int h1 = p1 / 7,  w1_ = p1 - h1*7;
            rowcode[r] = i1*169 + h1*13 + w1_;
        }
        #pragma unroll
        for (int t = 0; t < 19; ++t) {
            const int s2 = t*16 + c16;
            const int s2c = (s2 < SS) ? s2 : 293;
            const int j2 = s2c / 49, p2 = s2c - j2*49;
            const int h2 = p2 / 7,  w2_ = p2 - h2*7;
            const int cc = j2*169 + h2*13 + w2_;
            #pragma unroll
            for (int r = 0; r < 4; ++r)
                acc[t][r] += bias_table[(rowcode[r] - cc + 929)*8 + m];
        }
        #pragma unroll
        for (int r = 0; r < 4; ++r)
            acc[18][r] = (c16 < 6) ? acc[18][r] : -1e30f;   // mask s2 >= 294

        // ---- softmax over s2 (rows live in reg r across 16-lane col groups) ----
        float mx[4], sm[4], inv[4];
        #pragma unroll
        for (int r = 0; r < 4; ++r) mx[r] = -1e30f;
        #pragma unroll
        for (int t = 0; t < 19; ++t)
            #pragma unroll
            for (int r = 0; r < 4; ++r) mx[r] = fmaxf(mx[r], acc[t][r]);
        #pragma unroll
        for (int off = 1; off < 16; off <<= 1)
            #pragma unroll
            for (int r = 0; r < 4; ++r) mx[r] = fmaxf(mx[r], __shfl_xor(mx[r], off));
        #pragma unroll
        for (int r = 0; r < 4; ++r) sm[r] = 0.f;
        #pragma unroll
        for (int t = 0; t < 19; ++t)
            #pragma unroll
            for (int r = 0; r < 4; ++r) { const float e = __expf(acc[t][r] - mx[r]); acc[t][r] = e; sm[r] += e; }
        #pragma unroll
        for (int off = 1; off < 16; off <<= 1)
            #pragma unroll
            for (int r = 0; r < 4; ++r) sm[r] += __shfl_xor(sm[r], off);
        #pragma unroll
        for (int r = 0; r < 4; ++r) inv[r] = 1.0f / sm[r];
        #pragma unroll
        for (int t = 0; t < 19; ++t)
            #pragma unroll
            for (int r = 0; r < 4; ++r)
                strip_w[(g4*4 + r)*328 + t*16 + c16] = bfbits(acc[t][r] * inv[r]);

        // ---- phase D: PV (aggF over all s2; agg0 over j=0 via zero-padded v0) ----
        f32x4 aggF0 = zero4, aggF1 = zero4, agg00 = zero4, agg01 = zero4;
        bf16x8 asave0, asave1;
        #pragma unroll
        for (int ks = 0; ks < 10; ++ks) {
            const bf16x8 ap  = *(const bf16x8*)(strip_w + c16*328 + ks*32 + g4*8);
            const bf16x8 bv0 = *(const bf16x8*)(vT + (c16     )*328 + ks*32 + g4*8);
            const bf16x8 bv1 = *(const bf16x8*)(vT + (16 + c16)*328 + ks*32 + g4*8);
            aggF0 = mfma16(ap, bv0, aggF0);
            aggF1 = mfma16(ap, bv1, aggF1);
            if (ks == 0) asave0 = ap;
            if (ks == 1) asave1 = ap;
        }
        {
            const bf16x8 b00 = *(const bf16x8*)(vT0 + (c16     )*72 +      g4*8);
            const bf16x8 b01 = *(const bf16x8*)(vT0 + (16 + c16)*72 +      g4*8);
            const bf16x8 b10 = *(const bf16x8*)(vT0 + (c16     )*72 + 32 + g4*8);
            const bf16x8 b11 = *(const bf16x8*)(vT0 + (16 + c16)*72 + 32 + g4*8);
            agg00 = mfma16(asave0, b00, agg00); agg00 = mfma16(asave1, b10, agg00);
            agg01 = mfma16(asave0, b01, agg01); agg01 = mfma16(asave1, b11, agg01);
        }
        const f32x4 agg10 = aggF0 - agg00;
        const f32x4 agg11 = aggF1 - agg01;

        // ---- phase E: out = agg0 @ Wmsg[pair0]^T + agg1 @ Wmsg[pair1]^T ----
        #pragma unroll
        for (int r = 0; r < 4; ++r) {
            const int row = g4*4 + r;
            qws_w[row*72 +      c16] = bfbits(agg00[r]);
            qws_w[row*72 + 16 + c16] = bfbits(agg01[r]);
            qws_w[row*72 + 32 + c16] = bfbits(agg10[r]);
            qws_w[row*72 + 48 + c16] = bfbits(agg11[r]);
        }
        const bf16x8 aA0 = *(const bf16x8*)(qws_w + c16*72 +      g4*8);
        const bf16x8 aA1 = *(const bf16x8*)(qws_w + c16*72 + 32 + g4*8);
        const u16* mb0 = rmb + (pair0*HEADS + m)*1024;
        const u16* mb1 = rmb + (pair1*HEADS + m)*1024;
        const bf16x8 bm00 = *(const bf16x8*)(mb0 + (c16     )*32 + g4*8);
        const bf16x8 bm01 = *(const bf16x8*)(mb0 + (16 + c16)*32 + g4*8);
        const bf16x8 bm10 = *(const bf16x8*)(mb1 + (c16     )*32 + g4*8);
        const bf16x8 bm11 = *(const bf16x8*)(mb1 + (16 + c16)*32 + g4*8);
        f32x4 out0 = mfma16(aA0, bm00, zero4); out0 = mfma16(aA1, bm10, out0);
        f32x4 out1 = mfma16(aA0, bm01, zero4); out1 = mfma16(aA1, bm11, out1);

        // ---- store (C layout: col=c16, row=4*g4+r) ----
        #pragma unroll
        for (int r = 0; r < 4; ++r) {
            const int s1row = tile*16 + g4*4 + r;
            bool valid = (s1row < SS);
            if (job == 3)  valid = valid && (s1row == 48);
            if (job == 19) valid = valid && (s1row >= 49);
            if (valid) {
                const int i = s1row / 49, p = s1row - i*49;
                const size_t rb = ((size_t)((b*LL + i)*NWIN + nwin)*PP + p)*DIMM + m*CHN;
                o_pre[rb + c16]      = out0[r];
                o_pre[rb + 16 + c16] = out1[r];
            }
        }
    }
}

// ---------------- kernel 3: out = o_pre @ Wo^T ----------------
__global__ __launch_bounds__(256) void k_out(
    const float* __restrict__ pre, const float* __restrict__ WoT,
    float* __restrict__ out)
{
    __shared__ float xs[PP*DIMM];
    const int tid = threadIdx.x;
    const int bid = blockIdx.x;
    const float* xp = pre + (size_t)bid * (PP*DIMM);
    for (int idx = tid; idx < PP*DIMM; idx += 256) xs[idx] = xp[idx];
    __syncthreads();
    float* op = out + (size_t)bid * (PP*DIMM);
    {
        float acc[17];
        #pragma unroll
        for (int r = 0; r < 17; ++r) acc[r] = 0.f;
        gemm_rows<17>(xs, WoT, tid, 0, acc);
        #pragma unroll
        for (int r = 0; r < 17; ++r) op[(size_t)(0 + r)*DIMM + tid] = acc[r];
    }
    {
        float acc[16];
        #pragma unroll
        for (int r = 0; r < 16; ++r) acc[r] = 0.f;
        gemm_rows<16>(xs, WoT, tid, 17, acc);
        #pragma unroll
        for (int r = 0; r < 16; ++r) op[(size_t)(17 + r)*DIMM + tid] = acc[r];
    }
    {
        float acc[16];
        #pragma unroll
        for (int r = 0; r < 16; ++r) acc[r] = 0.f;
        gemm_rows<16>(xs, WoT, tid, 33, acc);
        #pragma unroll
        for (int r = 0; r < 16; ++r) op[(size_t)(33 + r)*DIMM + tid] = acc[r];
    }
}

extern "C" void kernel_launch(void* const* d_in, const int* in_sizes, int n_in,
                              void* d_out, int out_size, void* d_ws, size_t ws_size,
                              hipStream_t stream)
{
    (void)in_sizes; (void)n_in; (void)ws_size;
    const float* x        = (const float*)d_in[0];
    const float* Wq       = (const float*)d_in[1];
    const float* bq       = (const float*)d_in[2];
    const float* Wk       = (const float*)d_in[3];
    const float* bk       = (const float*)d_in[4];
    const float* Wv       = (const float*)d_in[5];
    const float* bv       = (const float*)d_in[6];
    const float* rel_att  = (const float*)d_in[7];
    const float* rel_msg  = (const float*)d_in[8];
    const float* bias_tab = (const float*)d_in[9];
    const float* Wo       = (const float*)d_in[10];
    const int*   atype    = (const int*)d_in[11];
    float* out = (float*)d_out;

    // workspace (unchanged from R1, 96.6 MB):
    char* ws = (char*)d_ws;
    float* WoT  = (float*)ws;
    bf16*  qb   = (bf16*)(ws + 262144);
    bf16*  kb   = (bf16*)(ws + 262144 + 1*19267584);
    bf16*  vb   = (bf16*)(ws + 262144 + 2*19267584);
    float* o_pre= (float*)(ws + 262144 + 3*19267584);

    // rel-weight bf16 copies live in the tail of d_out (overwritten later by k_out)
    u16* raT = (u16*)(out + (size_t)out_size - 32768);   // 65536 B
    u16* rmb = raT + 32768;                              // 65536 B

    k_transpose<<<dim3(8, 8), dim3(32, 8), 0, stream>>>(Wo, WoT);
    k_prep<<<128, 256, 0, stream>>>(rel_att, rel_msg, raT, rmb);
    k_qkv<<<BB*LL*NWIN, 256, 0, stream>>>(x, Wq, bq, Wk, bk, Wv, bv, atype, qb, kb, vb);
    k_attn<<<BB*NWIN*HEADS, 256, 76800, stream>>>((const u16*)qb, (const u16*)kb, (const u16*)vb,
                                                  raT, rmb, bias_tab, atype, o_pre);
    k_out<<<BB*LL*NWIN, 256, 0, stream>>>(o_pre, WoT, out);
}

// Round 3
// 299.807 us; speedup vs baseline: 22.2136x; 1.9836x over previous
//
#include <hip/hip_runtime.h>
#include <hip/hip_bf16.h>

typedef __hip_bfloat16 bf16;
typedef unsigned short u16;
typedef short bf16x8 __attribute__((ext_vector_type(8)));
typedef float f32x4  __attribute__((ext_vector_type(4)));

// problem constants (fixed instance)
#define BB    2
#define LL    6
#define NWIN  64     // X*Y
#define PP    49     // w1*w2
#define DIMM  256
#define HEADS 8
#define CHN   32
#define SS    294    // LL*PP
#define ASTRIDE 264  // LDS A-tile row stride in u16 (528 B: 16B-aligned, 2-way-free banks)

__device__ __forceinline__ u16 bfbits(float x) { return __bfloat16_as_ushort(__float2bfloat16(x)); }
__device__ __forceinline__ f32x4 mfma16(bf16x8 a, bf16x8 b, f32x4 c) {
    return __builtin_amdgcn_mfma_f32_16x16x32_bf16(a, b, c, 0, 0, 0);
}

// ---------------- prep 1: transpose+convert projection weights, convert Wo ----------------
// wT layout: [(tz*2+t)][e][d] bf16 (tz: 0=q,1=k,2=v), Wob: [e][d] bf16
__global__ __launch_bounds__(256) void k_prep_w(
    const float* __restrict__ Wq, const float* __restrict__ Wk, const float* __restrict__ Wv,
    const float* __restrict__ Wo, u16* __restrict__ wT, u16* __restrict__ Wob)
{
    const int idx = blockIdx.x*256 + threadIdx.x;
    if (idx >= 7*65536) return;
    const int mat = idx >> 16, rem = idx & 65535;
    if (mat < 6) {
        const int tz = mat >> 1, t = mat & 1;
        const int e = rem >> 8, d = rem & 255;
        const float* W = (tz == 0 ? Wq : tz == 1 ? Wk : Wv);
        wT[mat*65536 + rem] = bfbits(W[t*65536 + d*256 + e]);
    } else {
        Wob[rem] = bfbits(Wo[rem]);
    }
}

// ---------------- prep 2: rel weights to bf16 (att transposed) ----------------
__global__ __launch_bounds__(256) void k_prep_rel(const float* __restrict__ ra,
                                                  const float* __restrict__ rm,
                                                  u16* __restrict__ raT, u16* __restrict__ rmb)
{
    const int idx = blockIdx.x*256 + threadIdx.x;
    if (idx < 4*HEADS*CHN*CHN) {
        const int pm = idx >> 10, cf = idx & 1023, c = cf >> 5, f = cf & 31;
        raT[(pm << 10) + (f << 5) + c] = bfbits(ra[idx]);   // [pair][m][f][c]
        rmb[idx] = bfbits(rm[idx]);                          // [pair][m][c][f]
    }
}

// ---------------- kernel 1: QKV projection via MFMA ----------------
// block = (b,l,n): M=49(pad 64) x K=256 x N=256 for each of q,k,v.
__global__ __launch_bounds__(256) void k_qkv2(
    const float* __restrict__ x, const u16* __restrict__ wT,
    const float* __restrict__ bq, const float* __restrict__ bk, const float* __restrict__ bv,
    const int* __restrict__ atype,
    u16* __restrict__ q, u16* __restrict__ k, u16* __restrict__ v)
{
    __shared__ __align__(16) u16 As[64*ASTRIDE]; // 33792 B
    const int tid = threadIdx.x;
    const int w = tid >> 6, lane = tid & 63;
    const int g4 = lane >> 4, c16 = lane & 15;
    const int bid = blockIdx.x;              // (b*6+l)*64+n
    const int nwin = bid & 63;
    const int l = (bid >> 6) % LL;
    const int b = bid / (LL*NWIN);

    // stage x -> bf16 LDS
    const float4* xp = (const float4*)(x + (size_t)bid * (PP*DIMM));
    for (int idx = tid; idx < 49*64; idx += 256) {
        const int row = idx >> 6, c4 = idx & 63;
        const float4 xv = xp[idx];
        ushort4 h;
        h.x = bfbits(xv.x); h.y = bfbits(xv.y); h.z = bfbits(xv.z); h.w = bfbits(xv.w);
        *(ushort4*)&As[row*ASTRIDE + c4*4] = h;
    }
    const ushort4 z4 = {0, 0, 0, 0};
    for (int idx = tid; idx < 15*66; idx += 256) {
        const int row = 49 + idx/66, c4 = idx%66;
        *(ushort4*)&As[row*ASTRIDE + c4*4] = z4;
    }
    __syncthreads();

    const int t = (l == 0) ? 0 : atype[0];
    const f32x4 zero4 = {0.f, 0.f, 0.f, 0.f};

    for (int tz = 0; tz < 3; ++tz) {
        const u16* WT = wT + (size_t)(tz*2 + t)*65536;
        const float* bias = (tz == 0 ? bq : tz == 1 ? bk : bv) + t*DIMM;
        u16* dst = (tz == 0 ? q : tz == 1 ? k : v);
        const float scale = (tz == 0) ? 0.17677669529663687f : 1.0f;

        f32x4 acc[4][4];
        #pragma unroll
        for (int mm = 0; mm < 4; ++mm)
            #pragma unroll
            for (int nn = 0; nn < 4; ++nn) acc[mm][nn] = zero4;

        for (int ks = 0; ks < 8; ++ks) {
            bf16x8 a[4], bb[4];
            #pragma unroll
            for (int mm = 0; mm < 4; ++mm)
                a[mm] = *(const bf16x8*)&As[(mm*16 + c16)*ASTRIDE + ks*32 + g4*8];
            #pragma unroll
            for (int nn = 0; nn < 4; ++nn)
                bb[nn] = *(const bf16x8*)&WT[(size_t)(w*64 + nn*16 + c16)*256 + ks*32 + g4*8];
            #pragma unroll
            for (int mm = 0; mm < 4; ++mm)
                #pragma unroll
                for (int nn = 0; nn < 4; ++nn)
                    acc[mm][nn] = mfma16(a[mm], bb[nn], acc[mm][nn]);
        }

        // epilogue: +bias, *scale, bf16 store to head-major layout
        #pragma unroll
        for (int nn = 0; nn < 4; ++nn) {
            const int col = w*64 + nn*16 + c16;
            const float bval = bias[col];
            const int head = col >> 5, c = col & 31;
            const size_t base = (((size_t)(b*NWIN + nwin)*HEADS + head)*SS + l*PP)*CHN + c;
            #pragma unroll
            for (int mm = 0; mm < 4; ++mm) {
                #pragma unroll
                for (int r = 0; r < 4; ++r) {
                    const int row = mm*16 + g4*4 + r;
                    if (row < PP)
                        dst[base + (size_t)row*CHN] = bfbits((acc[mm][nn][r] + bval)*scale);
                }
            }
        }
    }
}

// ---------------- kernel 2: MFMA hetero attention per (b,n,m) ----------------
__global__ __launch_bounds__(256) void k_attn(
    const u16* __restrict__ q, const u16* __restrict__ kk_, const u16* __restrict__ v,
    const u16* __restrict__ raT, const u16* __restrict__ rmb,
    const float* __restrict__ bias_table, const int* __restrict__ atype,
    u16* __restrict__ o_pre)
{
    extern __shared__ __align__(16) u16 lds[];
    u16* vT    = lds;            // [32][328]
    u16* vT0   = lds + 10496;    // [32][72]
    u16* qws   = lds + 12800;    // [4][16][72]
    u16* strip = lds + 17408;    // [4][16][328]

    const int tid  = threadIdx.x;
    const int w    = tid >> 6;
    const int lane = tid & 63;
    const int g4   = lane >> 4;
    const int c16  = lane & 15;
    const int bid  = blockIdx.x;       // (b*64+n)*8+m
    const int m    = bid & 7;
    const int nwin = (bid >> 3) & 63;
    const int b    = bid >> 9;
    const int at   = atype[0];

    const size_t slab = (size_t)bid * (SS*CHN);
    const u16* qs  = q   + slab;
    const u16* ksg = kk_ + slab;
    const u16* vsg = v   + slab;

    u16* qws_w   = qws   + w*(16*72);
    u16* strip_w = strip + w*(16*328);

    // ---- zero pads + stage vT/vT0 ----
    for (int idx = tid; idx < 32*26; idx += 256) vT[(idx/26)*328 + 294 + (idx%26)] = 0;
    for (int idx = tid; idx < 32*15; idx += 256) vT0[(idx/15)*72 + 49 + (idx%15)] = 0;
    for (int idx = tid; idx < 4*16*26; idx += 256) {
        const int ww = idx/(16*26), rem = idx%(16*26);
        strip[ww*(16*328) + (rem/26)*328 + 294 + (rem%26)] = 0;
    }
    for (int idx = tid; idx < SS*CHN/2; idx += 256) {
        const int s2 = idx >> 4;
        const int f2 = (idx & 15) << 1;
        const unsigned int val = *(const unsigned int*)(vsg + s2*CHN + f2);
        const u16 v0 = (u16)(val & 0xffff), v1 = (u16)(val >> 16);
        vT[f2*328 + s2] = v0;
        vT[(f2+1)*328 + s2] = v1;
        if (s2 < 49) { vT0[f2*72 + s2] = v0; vT0[(f2+1)*72 + s2] = v1; }
    }
    __syncthreads();

    const f32x4 zero4 = {0.f, 0.f, 0.f, 0.f};

    for (int job = w; job < 20; job += 4) {
        const int tile = (job == 19) ? 3 : job;
        const int tiv  = (job <= 3) ? 0 : at;
        const int pair0 = tiv*2;
        const int pair1 = tiv*2 + at;

        // ---- phase A: qw build ----
        const int rowA = tile*16 + c16;
        const bf16x8 aq = *(const bf16x8*)(qs + rowA*CHN + g4*8);
        f32x4 cqw00, cqw01, cqw10, cqw11;
        {
            const u16* base0 = raT + (pair0*HEADS + m)*1024;
            const u16* base1 = raT + (pair1*HEADS + m)*1024;
            const bf16x8 b00 = *(const bf16x8*)(base0 + (c16     )*32 + g4*8);
            const bf16x8 b01 = *(const bf16x8*)(base0 + (16 + c16)*32 + g4*8);
            const bf16x8 b10 = *(const bf16x8*)(base1 + (c16     )*32 + g4*8);
            const bf16x8 b11 = *(const bf16x8*)(base1 + (16 + c16)*32 + g4*8);
            cqw00 = mfma16(aq, b00, zero4);
            cqw01 = mfma16(aq, b01, zero4);
            cqw10 = mfma16(aq, b10, zero4);
            cqw11 = mfma16(aq, b11, zero4);
        }
        #pragma unroll
        for (int r = 0; r < 4; ++r) {
            const int row = g4*4 + r;
            qws_w[row*72 +      c16] = bfbits(cqw00[r]);
            qws_w[row*72 + 16 + c16] = bfbits(cqw01[r]);
            qws_w[row*72 + 32 + c16] = bfbits(cqw10[r]);
            qws_w[row*72 + 48 + c16] = bfbits(cqw11[r]);
        }
        const bf16x8 A0 = *(const bf16x8*)(qws_w + c16*72 +      g4*8);
        const bf16x8 A1 = *(const bf16x8*)(qws_w + c16*72 + 32 + g4*8);

        // ---- phase B: sim ----
        f32x4 acc[19];
        #pragma unroll
        for (int t = 0; t < 3; ++t) {
            const bf16x8 bk = *(const bf16x8*)(ksg + (t*16 + c16)*CHN + g4*8);
            acc[t] = mfma16(A0, bk, zero4);
        }
        {
            const bf16x8 bk = *(const bf16x8*)(ksg + (3*16 + c16)*CHN + g4*8);
            const f32x4 cA = mfma16(A0, bk, zero4);
            const f32x4 cB = mfma16(A1, bk, zero4);
            #pragma unroll
            for (int r = 0; r < 4; ++r) acc[3][r] = (c16 == 0) ? cA[r] : cB[r];
        }
        #pragma unroll
        for (int t = 4; t < 19; ++t) {
            const bf16x8 bk = *(const bf16x8*)(ksg + (t*16 + c16)*CHN + g4*8);
            acc[t] = mfma16(A1, bk, zero4);
        }

        // ---- bias ----
        int rowcode[4];
        #pragma unroll
        for (int r = 0; r < 4; ++r) {
            const int s1r = tile*16 + g4*4 + r;
            const int s1c = (s1r < SS) ? s1r : 0;
            const int i1 = s1c / 49, p1 = s1c - i1*49;
            const int h1 = p1 / 7,  w1_ = p1 - h1*7;
            rowcode[r] = i1*169 + h1*13 + w1_;
        }
        #pragma unroll
        for (int t = 0; t < 19; ++t) {
            const int s2 = t*16 + c16;
            const int s2c = (s2 < SS) ? s2 : 293;
            const int j2 = s2c / 49, p2 = s2c - j2*49;
            const int h2 = p2 / 7,  w2_ = p2 - h2*7;
            const int cc = j2*169 + h2*13 + w2_;
            #pragma unroll
            for (int r = 0; r < 4; ++r)
                acc[t][r] += bias_table[(rowcode[r] - cc + 929)*8 + m];
        }
        #pragma unroll
        for (int r = 0; r < 4; ++r)
            acc[18][r] = (c16 < 6) ? acc[18][r] : -1e30f;

        // ---- softmax ----
        float mx[4], sm[4], inv[4];
        #pragma unroll
        for (int r = 0; r < 4; ++r) mx[r] = -1e30f;
        #pragma unroll
        for (int t = 0; t < 19; ++t)
            #pragma unroll
            for (int r = 0; r < 4; ++r) mx[r] = fmaxf(mx[r], acc[t][r]);
        #pragma unroll
        for (int off = 1; off < 16; off <<= 1)
            #pragma unroll
            for (int r = 0; r < 4; ++r) mx[r] = fmaxf(mx[r], __shfl_xor(mx[r], off));
        #pragma unroll
        for (int r = 0; r < 4; ++r) sm[r] = 0.f;
        #pragma unroll
        for (int t = 0; t < 19; ++t)
            #pragma unroll
            for (int r = 0; r < 4; ++r) { const float e = __expf(acc[t][r] - mx[r]); acc[t][r] = e; sm[r] += e; }
        #pragma unroll
        for (int off = 1; off < 16; off <<= 1)
            #pragma unroll
            for (int r = 0; r < 4; ++r) sm[r] += __shfl_xor(sm[r], off);
        #pragma unroll
        for (int r = 0; r < 4; ++r) inv[r] = 1.0f / sm[r];
        #pragma unroll
        for (int t = 0; t < 19; ++t)
            #pragma unroll
            for (int r = 0; r < 4; ++r)
                strip_w[(g4*4 + r)*328 + t*16 + c16] = bfbits(acc[t][r] * inv[r]);

        // ---- phase D: PV ----
        f32x4 aggF0 = zero4, aggF1 = zero4, agg00 = zero4, agg01 = zero4;
        bf16x8 asave0, asave1;
        #pragma unroll
        for (int ks = 0; ks < 10; ++ks) {
            const bf16x8 ap  = *(const bf16x8*)(strip_w + c16*328 + ks*32 + g4*8);
            const bf16x8 bv0 = *(const bf16x8*)(vT + (c16     )*328 + ks*32 + g4*8);
            const bf16x8 bv1 = *(const bf16x8*)(vT + (16 + c16)*328 + ks*32 + g4*8);
            aggF0 = mfma16(ap, bv0, aggF0);
            aggF1 = mfma16(ap, bv1, aggF1);
            if (ks == 0) asave0 = ap;
            if (ks == 1) asave1 = ap;
        }
        {
            const bf16x8 b00 = *(const bf16x8*)(vT0 + (c16     )*72 +      g4*8);
            const bf16x8 b01 = *(const bf16x8*)(vT0 + (16 + c16)*72 +      g4*8);
            const bf16x8 b10 = *(const bf16x8*)(vT0 + (c16     )*72 + 32 + g4*8);
            const bf16x8 b11 = *(const bf16x8*)(vT0 + (16 + c16)*72 + 32 + g4*8);
            agg00 = mfma16(asave0, b00, agg00); agg00 = mfma16(asave1, b10, agg00);
            agg01 = mfma16(asave0, b01, agg01); agg01 = mfma16(asave1, b11, agg01);
        }
        const f32x4 agg10 = aggF0 - agg00;
        const f32x4 agg11 = aggF1 - agg01;

        // ---- phase E: msg transform ----
        #pragma unroll
        for (int r = 0; r < 4; ++r) {
            const int row = g4*4 + r;
            qws_w[row*72 +      c16] = bfbits(agg00[r]);
            qws_w[row*72 + 16 + c16] = bfbits(agg01[r]);
            qws_w[row*72 + 32 + c16] = bfbits(agg10[r]);
            qws_w[row*72 + 48 + c16] = bfbits(agg11[r]);
        }
        const bf16x8 aA0 = *(const bf16x8*)(qws_w + c16*72 +      g4*8);
        const bf16x8 aA1 = *(const bf16x8*)(qws_w + c16*72 + 32 + g4*8);
        const u16* mb0 = rmb + (pair0*HEADS + m)*1024;
        const u16* mb1 = rmb + (pair1*HEADS + m)*1024;
        const bf16x8 bm00 = *(const bf16x8*)(mb0 + (c16     )*32 + g4*8);
        const bf16x8 bm01 = *(const bf16x8*)(mb0 + (16 + c16)*32 + g4*8);
        const bf16x8 bm10 = *(const bf16x8*)(mb1 + (c16     )*32 + g4*8);
        const bf16x8 bm11 = *(const bf16x8*)(mb1 + (16 + c16)*32 + g4*8);
        f32x4 out0 = mfma16(aA0, bm00, zero4); out0 = mfma16(aA1, bm10, out0);
        f32x4 out1 = mfma16(aA0, bm01, zero4); out1 = mfma16(aA1, bm11, out1);

        // ---- store bf16 ----
        #pragma unroll
        for (int r = 0; r < 4; ++r) {
            const int s1row = tile*16 + g4*4 + r;
            bool valid = (s1row < SS);
            if (job == 3)  valid = valid && (s1row == 48);
            if (job == 19) valid = valid && (s1row >= 49);
            if (valid) {
                const int i = s1row / 49, p = s1row - i*49;
                const size_t rb = ((size_t)((b*LL + i)*NWIN + nwin)*PP + p)*DIMM + m*CHN;
                o_pre[rb + c16]      = bfbits(out0[r]);
                o_pre[rb + 16 + c16] = bfbits(out1[r]);
            }
        }
    }
}

// ---------------- kernel 3: out = o_pre @ Wo^T via MFMA ----------------
__global__ __launch_bounds__(256) void k_out2(
    const u16* __restrict__ pre, const u16* __restrict__ Wob,
    float* __restrict__ out)
{
    __shared__ __align__(16) u16 As[64*ASTRIDE];
    const int tid = threadIdx.x;
    const int w = tid >> 6, lane = tid & 63;
    const int g4 = lane >> 4, c16 = lane & 15;
    const int bid = blockIdx.x;

    const uint4* pp = (const uint4*)(pre + (size_t)bid * (PP*DIMM));
    for (int idx = tid; idx < 49*32; idx += 256) {
        const int row = idx >> 5, c8 = idx & 31;
        *(uint4*)&As[row*ASTRIDE + c8*8] = pp[idx];
    }
    const ushort4 z4 = {0, 0, 0, 0};
    for (int idx = tid; idx < 15*66; idx += 256) {
        const int row = 49 + idx/66, c4 = idx%66;
        *(ushort4*)&As[row*ASTRIDE + c4*4] = z4;
    }
    __syncthreads();

    const f32x4 zero4 = {0.f, 0.f, 0.f, 0.f};
    f32x4 acc[4][4];
    #pragma unroll
    for (int mm = 0; mm < 4; ++mm)
        #pragma unroll
        for (int nn = 0; nn < 4; ++nn) acc[mm][nn] = zero4;

    for (int ks = 0; ks < 8; ++ks) {
        bf16x8 a[4], bb[4];
        #pragma unroll
        for (int mm = 0; mm < 4; ++mm)
            a[mm] = *(const bf16x8*)&As[(mm*16 + c16)*ASTRIDE + ks*32 + g4*8];
        #pragma unroll
        for (int nn = 0; nn < 4; ++nn)
            bb[nn] = *(const bf16x8*)&Wob[(size_t)(w*64 + nn*16 + c16)*256 + ks*32 + g4*8];
        #pragma unroll
        for (int mm = 0; mm < 4; ++mm)
            #pragma unroll
            for (int nn = 0; nn < 4; ++nn)
                acc[mm][nn] = mfma16(a[mm], bb[nn], acc[mm][nn]);
    }

    float* op = out + (size_t)bid * (PP*DIMM);
    #pragma unroll
    for (int nn = 0; nn < 4; ++nn) {
        const int col = w*64 + nn*16 + c16;
        #pragma unroll
        for (int mm = 0; mm < 4; ++mm) {
            #pragma unroll
            for (int r = 0; r < 4; ++r) {
                const int row = mm*16 + g4*4 + r;
                if (row < PP) op[(size_t)row*DIMM + col] = acc[mm][nn][r];
            }
        }
    }
}

extern "C" void kernel_launch(void* const* d_in, const int* in_sizes, int n_in,
                              void* d_out, int out_size, void* d_ws, size_t ws_size,
                              hipStream_t stream)
{
    (void)in_sizes; (void)n_in; (void)out_size; (void)ws_size;
    const float* x        = (const float*)d_in[0];
    const float* Wq       = (const float*)d_in[1];
    const float* bq       = (const float*)d_in[2];
    const float* Wk       = (const float*)d_in[3];
    const float* bk       = (const float*)d_in[4];
    const float* Wv       = (const float*)d_in[5];
    const float* bv       = (const float*)d_in[6];
    const float* rel_att  = (const float*)d_in[7];
    const float* rel_msg  = (const float*)d_in[8];
    const float* bias_tab = (const float*)d_in[9];
    const float* Wo       = (const float*)d_in[10];
    const int*   atype    = (const int*)d_in[11];
    float* out = (float*)d_out;

    // workspace layout (bytes):
    //  wT   bf16: [0,            786432)      3 mats x 2 types x 256x256
    //  Wob  bf16: [786432,       917504)
    //  raT  bf16: [917504,       983040)
    //  rmb  bf16: [983040,       1048576)
    //  qb   bf16: [1048576,     +19267584)
    //  kb   bf16: next
    //  vb   bf16: next
    //  o_preb bf16: next        -> total 78,118,912 B
    char* ws = (char*)d_ws;
    u16* wT   = (u16*)ws;
    u16* Wob  = (u16*)(ws + 786432);
    u16* raT  = (u16*)(ws + 917504);
    u16* rmb  = (u16*)(ws + 983040);
    u16* qb   = (u16*)(ws + 1048576);
    u16* kb   = (u16*)(ws + 1048576 + 1ull*19267584);
    u16* vb   = (u16*)(ws + 1048576 + 2ull*19267584);
    u16* o_preb = (u16*)(ws + 1048576 + 3ull*19267584);

    k_prep_w<<<1792, 256, 0, stream>>>(Wq, Wk, Wv, Wo, wT, Wob);
    k_prep_rel<<<128, 256, 0, stream>>>(rel_att, rel_msg, raT, rmb);
    k_qkv2<<<BB*LL*NWIN, 256, 0, stream>>>(x, wT, bq, bk, bv, atype, qb, kb, vb);
    k_attn<<<BB*NWIN*HEADS, 256, 76800, stream>>>(qb, kb, vb, raT, rmb, bias_tab, atype, o_preb);
    k_out2<<<BB*LL*NWIN, 256, 0, stream>>>(o_preb, Wob, out);
}